// Round 5
// baseline (227.649 us; speedup 1.0000x reference)
//
#include <hip/hip_runtime.h>

// PointNetSaModule fused — f32 in/out, f16 MFMA compute.
// R11: occupancy + MLP attack. R10 post-mortem: three different LDS structures
// (R5/R6/R10) all land 83-85us; DS-pipe reduction and conflict changes move
// nothing -> kernel is latency-bound at the shared invariant: 3 blocks/CU
// (47.6KB LDS), 3 waves/SIMD, long per-iter chain. R11:
//   - 1 point/wave (R5-proven): halves per-wave X LDS; LDS total 37,632B
//     -> 4 blocks/CU (16 waves, +33% occupancy), launch_bounds(256,4).
//   - depth-1 prefetch of ALL per-point data (pts frags, xyz, vmask, xyzs),
//     issued at iter top -> full iter of compute hides gather latency.
//   - s1sh/s2sh staging dropped (scales recomputed inline, setup-only).
// All R10-validated math kept: swapped L0/L1 (mfma(w,x), A/B frag maps
// identical), u32-pair LDS transpose (stride 36, b64 writes / b128 reads),
// padded-72 weight LDS, t1/t2 in tiny LDS, shfl_xor K-maxpool. NO permlane.

#define NGRP_    16384        // groups of 4 points (one per wave)
#define OUTHALF_ 8388608      // elements: second output copy offset
#define WS_      72           // padded f16 stride of W1'/W2' rows (need 64)
#define XS2_     36           // u32 stride of X' rows (need 32; 144B, 16B-mult)
#define EPS_     1e-5f
#define GRID_    1024         // 4 blocks/CU x 256 CUs, 16 iters/block exact

typedef _Float16 h8    __attribute__((ext_vector_type(8)));
typedef float    f32x4 __attribute__((ext_vector_type(4)));
typedef unsigned u32x2 __attribute__((ext_vector_type(2)));

__global__ __launch_bounds__(256) void cvt_pts_kernel(
    const float* __restrict__ src, _Float16* __restrict__ dst)
{
    const size_t i = ((size_t)blockIdx.x * 256 + threadIdx.x) * 8;
    f32x4 a = *(const f32x4*)(src + i);
    f32x4 b = *(const f32x4*)(src + i + 4);
    h8 o;
#pragma unroll
    for (int j = 0; j < 4; ++j) { o[j] = (_Float16)a[j]; o[4 + j] = (_Float16)b[j]; }
    *(h8*)(dst + i) = o;
}

// relu + cvt + pack two f32 into one u32 of 2 f16 (RTE casts, R6/R10 numerics)
#define PK(lo, hi) ({                                                          \
    const _Float16 _l = (_Float16)fmaxf((lo), 0.f);                            \
    const _Float16 _h = (_Float16)fmaxf((hi), 0.f);                            \
    (unsigned)__builtin_bit_cast(unsigned short, _l) |                         \
    ((unsigned)__builtin_bit_cast(unsigned short, _h) << 16); })

template<bool PRE>
__device__ __forceinline__ void load_pt(const void* __restrict__ ptsv,
                                        size_t row, int quad, h8& o0, h8& o1)
{
    if constexpr (PRE) {
        const _Float16* pw = (const _Float16*)ptsv + (row << 6);
        o0 = *(const h8*)(pw + quad * 8);
        o1 = *(const h8*)(pw + 32 + quad * 8);
    } else {
        const float* pw = (const float*)ptsv + (row << 6);
        f32x4 r0 = *(const f32x4*)(pw + quad * 8);
        f32x4 r1 = *(const f32x4*)(pw + quad * 8 + 4);
        f32x4 r2 = *(const f32x4*)(pw + 32 + quad * 8);
        f32x4 r3 = *(const f32x4*)(pw + 32 + quad * 8 + 4);
#pragma unroll
        for (int j = 0; j < 4; ++j) { o0[j]=(_Float16)r0[j]; o0[4+j]=(_Float16)r1[j];
                                      o1[j]=(_Float16)r2[j]; o1[4+j]=(_Float16)r3[j]; }
    }
}

template<bool PRE>   // PRE: pts pre-converted to f16 in workspace
__global__ __launch_bounds__(256, 4) void pnsa_main(
    const float* __restrict__ xyz,    // (B,HW,3) f32
    const void*  __restrict__ ptsv,   // f16 ws if PRE, else f32 (B,HW,64)
    const float* __restrict__ xyzs,   // (B,NPT,3) f32
    const int*   __restrict__ nidx,   // (B,NPT*16)
    const float* __restrict__ vmask,  // (B,NPT,16) f32
    const float* __restrict__ w0, const float* __restrict__ b0,
    const float* __restrict__ g0, const float* __restrict__ be0,
    const float* __restrict__ m0, const float* __restrict__ v0,
    const float* __restrict__ w1, const float* __restrict__ b1,
    const float* __restrict__ g1, const float* __restrict__ be1,
    const float* __restrict__ m1, const float* __restrict__ v1,
    const float* __restrict__ w2, const float* __restrict__ b2,
    const float* __restrict__ g2, const float* __restrict__ be2,
    const float* __restrict__ m2, const float* __restrict__ v2,
    float*       __restrict__ out)
{
    __shared__ __align__(16) _Float16 ldsW1[64 * WS_];       // W1'[n][k]  9216B
    __shared__ __align__(16) _Float16 ldsW2[128 * WS_];      // W2'[n][k] 18432B
    __shared__ __align__(16) float    t1sh[64];              //             256B
    __shared__ __align__(16) float    t2sh[128];             //             512B
    __shared__ __align__(16) unsigned ldsX[4][16 * XS2_];    // X' u32     9216B
    // total 37,632B -> 4 blocks/CU

    const int tid  = threadIdx.x;
    const int wave = tid >> 6;
    const int lane = tid & 63;
    const int l15  = lane & 15;
    const int quad = lane >> 4;

    unsigned* Xp = &ldsX[wave][0];

    // ---- shifted biases t1/t2; W1'/W2' BN-folded into LDS (scales inline) ----
    if (tid < 64) {
        const float s = g1[tid] * rsqrtf(v1[tid] + EPS_);
        t1sh[tid] = (b1[tid] - m1[tid]) * s + be1[tid];
    }
    if (tid < 128) {
        const float s = g2[tid] * rsqrtf(v2[tid] + EPS_);
        t2sh[tid] = (b2[tid] - m2[tid]) * s + be2[tid];
    }
    for (int idx = tid; idx < 64 * 64; idx += 256) {     // w1[k][n] -> W1'[n][k]
        const int k = idx >> 6, n = idx & 63;
        ldsW1[n * WS_ + k] = (_Float16)(w1[idx] * (g1[n] * rsqrtf(v1[n] + EPS_)));
    }
    for (int idx = tid; idx < 64 * 128; idx += 256) {    // w2[k][n] -> W2'[n][k]
        const int k = idx >> 7, n = idx & 127;
        ldsW2[n * WS_ + k] = (_Float16)(w2[idx] * (g2[n] * rsqrtf(v2[n] + EPS_)));
    }
    __syncthreads();

    // ---- W0 BN-folded into register frags; bias via pad channel 67 ----
    // Feature k-order: [points 0..63, xyz_diff 64..66, BIAS 67 (=1.0), pad..95]
    // Frag map (A==B on gfx950): lane holds [ch=nt*16+l15][k=kk*32+quad*8+j]
    h8 b0f[4][3];
#pragma unroll
    for (int nt = 0; nt < 4; ++nt) {
        const int ch = nt * 16 + l15;
        const float s = g0[ch] * rsqrtf(v0[ch] + EPS_);
        const float t0 = (b0[ch] - m0[ch]) * s + be0[ch];
#pragma unroll
        for (int kk = 0; kk < 3; ++kk) {
            h8 f;
#pragma unroll
            for (int j = 0; j < 8; ++j) {
                const int k = kk * 32 + quad * 8 + j;
                float wv = 0.f;
                if (k < 64)       wv = w0[(3 + k) * 64 + ch] * s;
                else if (k < 67)  wv = w0[(k - 64) * 64 + ch] * s;
                else if (k == 67) wv = t0;                 // bias via 1.0 channel
                f[j] = (_Float16)wv;
            }
            b0f[nt][kk] = f;
        }
    }

    // ---- main loop: 4 points per block iteration (1 per wave) ----
    // Rotating per-point state (depth-1 data prefetch):
    h8 q0, q1;
    float xg0, xg1, xg2, xs0, xs1, xs2, mk;
    int nb_nxt;
    {   // peel: load iter-0 data + iter-1 neighbor
        const int p = (blockIdx.x << 2) + wave;
        const int nb0 = nidx[(p << 4) + l15];
        const size_t row = (size_t)(((p >> 14) << 16) + nb0);
        load_pt<PRE>(ptsv, row, quad, q0, q1);
        const float* xgp = xyz + row * 3;
        xg0 = xgp[0]; xg1 = xgp[1]; xg2 = xgp[2];
        mk = vmask[(p << 4) + l15];
        const float* xsp = xyzs + (size_t)p * 3;
        xs0 = xsp[0]; xs1 = xsp[1]; xs2 = xsp[2];
        const int g1i = (blockIdx.x + GRID_ < NGRP_) ? blockIdx.x + GRID_ : blockIdx.x;
        nb_nxt = nidx[(((g1i << 2) + wave) << 4) + l15];
    }

    for (int grp = blockIdx.x; grp < NGRP_; grp += GRID_) {
        const int p = (grp << 2) + wave;
        const int gn  = (grp + GRID_ < NGRP_) ? grp + GRID_ : grp;
        const int gnn = (gn + GRID_ < NGRP_) ? gn + GRID_ : gn;
        const int pn  = (gn << 2) + wave;

        // ---- prefetch next-iter point data (latency hidden under compute) ----
        const size_t rowN = (size_t)(((pn >> 14) << 16) + nb_nxt);
        h8 q0n, q1n;
        load_pt<PRE>(ptsv, rowN, quad, q0n, q1n);
        const float* xgpn = xyz + rowN * 3;
        const float xg0n = xgpn[0], xg1n = xgpn[1], xg2n = xgpn[2];
        const float mkn = vmask[(pn << 4) + l15];
        const float* xspn = xyzs + (size_t)pn * 3;
        const float xs0n = xspn[0], xs1n = xspn[1], xs2n = xspn[2];
        const int nb_n2 = nidx[(((gnn << 2) + wave) << 4) + l15];

        // ---- current point: mask + xyz_diff/bias fragment ----
        h8 a0 = q0, a1 = q1;
        if (mk == 0.0f) { a0 = (h8)(_Float16)0.f; a1 = (h8)(_Float16)0.f; }
        h8 a2 = (h8)(_Float16)0.f;
        if (quad == 0) {
            a2[0] = (_Float16)(xg0 * mk - xs0);
            a2[1] = (_Float16)(xg1 * mk - xs1);
            a2[2] = (_Float16)(xg2 * mk - xs2);
            a2[3] = (_Float16)1.0f;               // bias channel
        }

        // ---- layer 0 SWAPPED: D = W0'' X^T -> acc[r] = X1[16nt+4q+r][nb=l15]
#pragma unroll
        for (int nt = 0; nt < 4; ++nt) {
            f32x4 acc = {0.f, 0.f, 0.f, 0.f};
            acc = __builtin_amdgcn_mfma_f32_16x16x32_f16(b0f[nt][0], a0, acc, 0, 0, 0);
            acc = __builtin_amdgcn_mfma_f32_16x16x32_f16(b0f[nt][1], a1, acc, 0, 0, 0);
            acc = __builtin_amdgcn_mfma_f32_16x16x32_f16(b0f[nt][2], a2, acc, 0, 0, 0);
            u32x2 pk = {PK(acc[0], acc[1]), PK(acc[2], acc[3])};
            *(u32x2*)(Xp + l15 * XS2_ + nt * 8 + quad * 2) = pk;
        }

        // ---- layer 1 SWAPPED (reads precede overwrites; DS in-order/wave) ----
        h8 x0 = *(const h8*)(Xp + l15 * XS2_ + quad * 4);
        h8 x1 = *(const h8*)(Xp + l15 * XS2_ + 16 + quad * 4);
#pragma unroll 2
        for (int nt = 0; nt < 4; ++nt) {
            const _Float16* wrow = ldsW1 + (nt * 16 + l15) * WS_ + quad * 8;
            h8 wa = *(const h8*)(wrow);
            h8 wb = *(const h8*)(wrow + 32);
            const f32x4 t1 = *(const f32x4*)(t1sh + nt * 16 + quad * 4);
            f32x4 acc = t1;              // bias in accumulator (ch = 16nt+4q+r)
            acc = __builtin_amdgcn_mfma_f32_16x16x32_f16(wa, x0, acc, 0, 0, 0);
            acc = __builtin_amdgcn_mfma_f32_16x16x32_f16(wb, x1, acc, 0, 0, 0);
            u32x2 pk = {PK(acc[0], acc[1]), PK(acc[2], acc[3])};
            *(u32x2*)(Xp + l15 * XS2_ + nt * 8 + quad * 2) = pk;
        }

        // ---- layer 2 NORMAL: A-operand from X + K-maxpool + stores ----
        h8 y0 = *(const h8*)(Xp + l15 * XS2_ + quad * 4);
        h8 y1 = *(const h8*)(Xp + l15 * XS2_ + 16 + quad * 4);
        float* ob = out + ((size_t)p << 7);
#pragma unroll 2
        for (int nt = 0; nt < 8; ++nt) {
            const _Float16* wrow = ldsW2 + (nt * 16 + l15) * WS_ + quad * 8;
            h8 wa = *(const h8*)(wrow);
            h8 wb = *(const h8*)(wrow + 32);
            const float t2 = t2sh[nt * 16 + l15];
            f32x4 acc = {0.f, 0.f, 0.f, 0.f};
            acc = __builtin_amdgcn_mfma_f32_16x16x32_f16(y0, wa, acc, 0, 0, 0);
            acc = __builtin_amdgcn_mfma_f32_16x16x32_f16(y1, wb, acc, 0, 0, 0);
            float v = fmaxf(fmaxf(acc[0], acc[1]), fmaxf(acc[2], acc[3])) + t2;
            v = fmaxf(v, 0.f);                        // relu(max)=max(relu)
            v = fmaxf(v, __shfl_xor(v, 16, 64));
            v = fmaxf(v, __shfl_xor(v, 32, 64));
            if (quad == 0) {
                ob[nt * 16 + l15]            = v;
                ob[OUTHALF_ + nt * 16 + l15] = v;
            }
        }

        // ---- rotate prefetched state ----
        q0 = q0n; q1 = q1n;
        xg0 = xg0n; xg1 = xg1n; xg2 = xg2n;
        xs0 = xs0n; xs1 = xs1n; xs2 = xs2n;
        mk = mkn; nb_nxt = nb_n2;
    }
}

extern "C" void kernel_launch(void* const* d_in, const int* in_sizes, int n_in,
                              void* d_out, int out_size, void* d_ws, size_t ws_size,
                              hipStream_t stream) {
    const float* xyz   = (const float*)d_in[0];
    const float* pts   = (const float*)d_in[1];
    const float* xyzs  = (const float*)d_in[2];
    const int*   nidx  = (const int*)d_in[3];
    const float* vmask = (const float*)d_in[4];
    const float *w0 = (const float*)d_in[5],  *b0 = (const float*)d_in[6],
                *g0 = (const float*)d_in[7],  *be0 = (const float*)d_in[8],
                *m0 = (const float*)d_in[9],  *v0 = (const float*)d_in[10];
    const float *w1 = (const float*)d_in[11], *b1 = (const float*)d_in[12],
                *g1 = (const float*)d_in[13], *be1 = (const float*)d_in[14],
                *m1 = (const float*)d_in[15], *v1 = (const float*)d_in[16];
    const float *w2 = (const float*)d_in[17], *b2 = (const float*)d_in[18],
                *g2 = (const float*)d_in[19], *be2 = (const float*)d_in[20],
                *m2 = (const float*)d_in[21], *v2 = (const float*)d_in[22];
    float* outp = (float*)d_out;

    const size_t PTS_ELEMS = 16777216ull;           // 4*65536*64
    if (ws_size >= PTS_ELEMS * sizeof(_Float16)) {
        _Float16* ptsh = (_Float16*)d_ws;
        cvt_pts_kernel<<<dim3(8192), dim3(256), 0, stream>>>(pts, ptsh);
        pnsa_main<true><<<dim3(GRID_), dim3(256), 0, stream>>>(
            xyz, (const void*)ptsh, xyzs, nidx, vmask,
            w0, b0, g0, be0, m0, v0,
            w1, b1, g1, be1, m1, v1,
            w2, b2, g2, be2, m2, v2, outp);
    } else {
        pnsa_main<false><<<dim3(GRID_), dim3(256), 0, stream>>>(
            xyz, (const void*)pts, xyzs, nidx, vmask,
            w0, b0, g0, be0, m0, v0,
            w1, b1, g1, be1, m1, v1,
            w2, b2, g2, be2, m2, v2, outp);
    }
}

// Round 6
// 222.941 us; speedup vs baseline: 1.0211x; 1.0211x over previous
//
#include <hip/hip_runtime.h>

// PointNetSaModule fused — f32 in/out, f16 MFMA compute.
// R12 = R10 base (84.5us verified: 2pt/wave, swapped L0/L1, u32-pair LDS
// transpose, (256,3)/768) + gather-latency attack:
//   1) depth-1 prefetch of ALL per-point data (pts frags, xyz, vmask, xyzs;
//      nidx at depth-2 since it feeds the gather address). A full iteration
//      of MFMA/LDS work now hides the ~300-900cy scattered-gather latency.
//   2) XCD-affinity grouping: block b -> XCD b&7 (round-robin dispatch);
//      each XCD owns a contiguous 1024-group range = ONE batch's 8MB pts
//      table (vs all 32MB) -> L2 hit ~12%->~50%. Bijective remap, same
//      10.67-iter balance; degrades to a permutation if dispatch differs.
// R11 post-mortem: 1pt/wave doubled per-point weight LDS reads (+conflicts)
// and VGPR=64 killed the prefetch; occupancy (28->37%) did NOT help ->
// keep 2pt/wave + 3 blocks/CU, spend registers on prefetch instead.

#define NGRP_    8192         // groups of 8 points (B*h*w/8)
#define GPX_     1024         // groups per XCD (NGRP_/8)
#define BPX_     96           // blocks per XCD (GRID_/8)
#define OUTHALF_ 8388608      // elements: second output copy offset
#define WS_      72           // padded f16 stride of W1'/W2' rows (need 64)
#define XS2_     36           // u32 stride of X' rows (need 32; 144B, 16B-mult)
#define EPS_     1e-5f
#define GRID_    768          // 3 blocks/CU x 256 CUs

typedef _Float16 h8    __attribute__((ext_vector_type(8)));
typedef float    f32x4 __attribute__((ext_vector_type(4)));
typedef unsigned u32x2 __attribute__((ext_vector_type(2)));

__global__ __launch_bounds__(256) void cvt_pts_kernel(
    const float* __restrict__ src, _Float16* __restrict__ dst)
{
    const size_t i = ((size_t)blockIdx.x * 256 + threadIdx.x) * 8;
    f32x4 a = *(const f32x4*)(src + i);
    f32x4 b = *(const f32x4*)(src + i + 4);
    h8 o;
#pragma unroll
    for (int j = 0; j < 4; ++j) { o[j] = (_Float16)a[j]; o[4 + j] = (_Float16)b[j]; }
    *(h8*)(dst + i) = o;
}

// relu + cvt + pack two f32 into one u32 of 2 f16 (RTE casts, R6/R10 numerics)
#define PK(lo, hi) ({                                                          \
    const _Float16 _l = (_Float16)fmaxf((lo), 0.f);                            \
    const _Float16 _h = (_Float16)fmaxf((hi), 0.f);                            \
    (unsigned)__builtin_bit_cast(unsigned short, _l) |                         \
    ((unsigned)__builtin_bit_cast(unsigned short, _h) << 16); })

// one point's gathered input bundle (all statically indexed -> registers)
struct PtData {
    h8 q0, q1;                       // 64 point-feature channels (f16)
    float xg0, xg1, xg2;             // gathered neighbor xyz
    float xs0, xs1, xs2;             // sampled-point xyz
    float mk;                        // valid mask
};

template<bool PRE>
__device__ __forceinline__ PtData load_point(
    const void* __restrict__ ptsv, const float* __restrict__ xyz,
    const float* __restrict__ xyzs, const float* __restrict__ vmask,
    int p, int nb, int quad, int l15)
{
    PtData d;
    const size_t row = (size_t)(((p >> 14) << 16) + nb);
    if constexpr (PRE) {
        const _Float16* pw = (const _Float16*)ptsv + (row << 6);
        d.q0 = *(const h8*)(pw + quad * 8);
        d.q1 = *(const h8*)(pw + 32 + quad * 8);
    } else {
        const float* pw = (const float*)ptsv + (row << 6);
        f32x4 r0 = *(const f32x4*)(pw + quad * 8);
        f32x4 r1 = *(const f32x4*)(pw + quad * 8 + 4);
        f32x4 r2 = *(const f32x4*)(pw + 32 + quad * 8);
        f32x4 r3 = *(const f32x4*)(pw + 32 + quad * 8 + 4);
#pragma unroll
        for (int j = 0; j < 4; ++j) { d.q0[j]=(_Float16)r0[j]; d.q0[4+j]=(_Float16)r1[j];
                                      d.q1[j]=(_Float16)r2[j]; d.q1[4+j]=(_Float16)r3[j]; }
    }
    const float* xgp = xyz + row * 3;
    d.xg0 = xgp[0]; d.xg1 = xgp[1]; d.xg2 = xgp[2];
    d.mk = vmask[(p << 4) + l15];
    const float* xsp = xyzs + (size_t)p * 3;
    d.xs0 = xsp[0]; d.xs1 = xsp[1]; d.xs2 = xsp[2];
    return d;
}

template<bool PRE>   // PRE: pts pre-converted to f16 in workspace
__global__ __launch_bounds__(256, 3) void pnsa_main(
    const float* __restrict__ xyz,    // (B,HW,3) f32
    const void*  __restrict__ ptsv,   // f16 ws if PRE, else f32 (B,HW,64)
    const float* __restrict__ xyzs,   // (B,NPT,3) f32
    const int*   __restrict__ nidx,   // (B,NPT*16)
    const float* __restrict__ vmask,  // (B,NPT,16) f32
    const float* __restrict__ w0, const float* __restrict__ b0,
    const float* __restrict__ g0, const float* __restrict__ be0,
    const float* __restrict__ m0, const float* __restrict__ v0,
    const float* __restrict__ w1, const float* __restrict__ b1,
    const float* __restrict__ g1, const float* __restrict__ be1,
    const float* __restrict__ m1, const float* __restrict__ v1,
    const float* __restrict__ w2, const float* __restrict__ b2,
    const float* __restrict__ g2, const float* __restrict__ be2,
    const float* __restrict__ m2, const float* __restrict__ v2,
    float*       __restrict__ out)
{
    __shared__ __align__(16) _Float16 ldsW1[64 * WS_];        // W1'[n][k]  9216B
    __shared__ __align__(16) _Float16 ldsW2[128 * WS_];       // W2'[n][k] 18432B
    __shared__ __align__(16) float    s1sh[64], t1sh[64];     //             512B
    __shared__ __align__(16) float    s2sh[128], t2sh[128];   //            1024B
    __shared__ __align__(16) unsigned ldsX[4][2][16 * XS2_];  // X' u32   18432B

    const int tid  = threadIdx.x;
    const int wave = tid >> 6;
    const int lane = tid & 63;
    const int l15  = lane & 15;
    const int quad = lane >> 4;

    unsigned* XA = &ldsX[wave][0][0];
    unsigned* XB = &ldsX[wave][1][0];

    // ---- stage BN scales + shifted biases, then W1'/W2' folded into LDS ----
    if (tid < 64) {
        const float s = g1[tid] * rsqrtf(v1[tid] + EPS_);
        s1sh[tid] = s;
        t1sh[tid] = (b1[tid] - m1[tid]) * s + be1[tid];
    }
    if (tid < 128) {
        const float s = g2[tid] * rsqrtf(v2[tid] + EPS_);
        s2sh[tid] = s;
        t2sh[tid] = (b2[tid] - m2[tid]) * s + be2[tid];
    }
    __syncthreads();
    for (int idx = tid; idx < 64 * 64; idx += 256) {     // w1[k][n] -> W1'[n][k]
        const int k = idx >> 6, n = idx & 63;
        ldsW1[n * WS_ + k] = (_Float16)(w1[idx] * s1sh[n]);
    }
    for (int idx = tid; idx < 64 * 128; idx += 256) {    // w2[k][n] -> W2'[n][k]
        const int k = idx >> 7, n = idx & 127;
        ldsW2[n * WS_ + k] = (_Float16)(w2[idx] * s2sh[n]);
    }
    __syncthreads();

    // ---- W0 BN-folded into register frags; bias via pad channel 67 ----
    // Feature k-order: [points 0..63, xyz_diff 64..66, BIAS 67 (=1.0), pad..95]
    // Frag map (A==B on gfx950): lane holds [ch=nt*16+l15][k=kk*32+quad*8+j]
    h8 b0f[4][3];
#pragma unroll
    for (int nt = 0; nt < 4; ++nt) {
        const int ch = nt * 16 + l15;
        const float s = g0[ch] * rsqrtf(v0[ch] + EPS_);
        const float t0 = (b0[ch] - m0[ch]) * s + be0[ch];
#pragma unroll
        for (int kk = 0; kk < 3; ++kk) {
            h8 f;
#pragma unroll
            for (int j = 0; j < 8; ++j) {
                const int k = kk * 32 + quad * 8 + j;
                float wv = 0.f;
                if (k < 64)       wv = w0[(3 + k) * 64 + ch] * s;
                else if (k < 67)  wv = w0[(k - 64) * 64 + ch] * s;
                else if (k == 67) wv = t0;                 // bias via 1.0 channel
                f[j] = (_Float16)wv;
            }
            b0f[nt][kk] = f;
        }
    }

    // ---- XCD-affinity mapping: block b -> XCD b&7, contiguous grp range ----
    const int xcd = blockIdx.x & 7;          // round-robin dispatch assumption
    const int bix = blockIdx.x >> 3;         // 0..95 within XCD
    const int gbase = xcd * GPX_;            // this XCD's 1024-group range

    // ---- peel: load iter-0 data (depth-1) + iter-1 neighbors (depth-2) ----
    PtData dA, dB;
    int nbA_nxt, nbB_nxt;
    {
        const int grp0 = gbase + bix;
        const int pA0 = (grp0 << 3) + (wave << 1);
        const int nbA0 = nidx[(pA0 << 4) + l15];
        const int nbB0 = nidx[((pA0 + 1) << 4) + l15];
        dA = load_point<PRE>(ptsv, xyz, xyzs, vmask, pA0,     nbA0, quad, l15);
        dB = load_point<PRE>(ptsv, xyz, xyzs, vmask, pA0 + 1, nbB0, quad, l15);
        const int g1i = (bix + BPX_ < GPX_) ? bix + BPX_ : bix;
        const int pA1 = ((gbase + g1i) << 3) + (wave << 1);
        nbA_nxt = nidx[(pA1 << 4) + l15];
        nbB_nxt = nidx[((pA1 + 1) << 4) + l15];
    }

    for (int g = bix; g < GPX_; g += BPX_) {
        const int grp = gbase + g;
        const int pA = (grp << 3) + (wave << 1);
        const int pB = pA + 1;
        const int gn  = (g + BPX_ < GPX_) ? g + BPX_ : g;
        const int gnn = (gn + BPX_ < GPX_) ? gn + BPX_ : gn;
        const int pAn = ((gbase + gn) << 3) + (wave << 1);
        const int pA2 = ((gbase + gnn) << 3) + (wave << 1);

        // ---- prefetch next-iter point data + next-next neighbors ----
        PtData dAn = load_point<PRE>(ptsv, xyz, xyzs, vmask, pAn,     nbA_nxt, quad, l15);
        PtData dBn = load_point<PRE>(ptsv, xyz, xyzs, vmask, pAn + 1, nbB_nxt, quad, l15);
        const int nbA_n2 = nidx[(pA2 << 4) + l15];
        const int nbB_n2 = nidx[((pA2 + 1) << 4) + l15];

        // ---- current points: mask + xyz_diff/bias fragment ----
        h8 qA0 = dA.q0, qA1 = dA.q1, qB0 = dB.q0, qB1 = dB.q1;
        if (dA.mk == 0.0f) { qA0 = (h8)(_Float16)0.f; qA1 = (h8)(_Float16)0.f; }
        if (dB.mk == 0.0f) { qB0 = (h8)(_Float16)0.f; qB1 = (h8)(_Float16)0.f; }
        h8 aA2 = (h8)(_Float16)0.f, aB2 = (h8)(_Float16)0.f;
        if (quad == 0) {
            aA2[0] = (_Float16)(dA.xg0 * dA.mk - dA.xs0);
            aA2[1] = (_Float16)(dA.xg1 * dA.mk - dA.xs1);
            aA2[2] = (_Float16)(dA.xg2 * dA.mk - dA.xs2);
            aA2[3] = (_Float16)1.0f;               // bias channel
            aB2[0] = (_Float16)(dB.xg0 * dB.mk - dB.xs0);
            aB2[1] = (_Float16)(dB.xg1 * dB.mk - dB.xs1);
            aB2[2] = (_Float16)(dB.xg2 * dB.mk - dB.xs2);
            aB2[3] = (_Float16)1.0f;
        }

        // ---- layer 0 SWAPPED: D = W0'' X^T -> acc[r] = X1[16nt+4q+r][nb=l15]
#pragma unroll
        for (int nt = 0; nt < 4; ++nt) {
            f32x4 aA = {0.f,0.f,0.f,0.f}, aB = {0.f,0.f,0.f,0.f};
            aA = __builtin_amdgcn_mfma_f32_16x16x32_f16(b0f[nt][0], qA0, aA, 0, 0, 0);
            aA = __builtin_amdgcn_mfma_f32_16x16x32_f16(b0f[nt][1], qA1, aA, 0, 0, 0);
            aA = __builtin_amdgcn_mfma_f32_16x16x32_f16(b0f[nt][2], aA2, aA, 0, 0, 0);
            aB = __builtin_amdgcn_mfma_f32_16x16x32_f16(b0f[nt][0], qB0, aB, 0, 0, 0);
            aB = __builtin_amdgcn_mfma_f32_16x16x32_f16(b0f[nt][1], qB1, aB, 0, 0, 0);
            aB = __builtin_amdgcn_mfma_f32_16x16x32_f16(b0f[nt][2], aB2, aB, 0, 0, 0);
            u32x2 pkA = {PK(aA[0], aA[1]), PK(aA[2], aA[3])};
            u32x2 pkB = {PK(aB[0], aB[1]), PK(aB[2], aB[3])};
            *(u32x2*)(XA + l15 * XS2_ + nt * 8 + quad * 2) = pkA;
            *(u32x2*)(XB + l15 * XS2_ + nt * 8 + quad * 2) = pkB;
        }

        // ---- layer 1 SWAPPED (reads precede overwrites; DS in-order/wave) ----
        h8 xA0 = *(const h8*)(XA + l15 * XS2_ + quad * 4);
        h8 xA1 = *(const h8*)(XA + l15 * XS2_ + 16 + quad * 4);
        h8 xB0 = *(const h8*)(XB + l15 * XS2_ + quad * 4);
        h8 xB1 = *(const h8*)(XB + l15 * XS2_ + 16 + quad * 4);
#pragma unroll 2
        for (int nt = 0; nt < 4; ++nt) {
            const _Float16* wrow = ldsW1 + (nt * 16 + l15) * WS_ + quad * 8;
            h8 wa = *(const h8*)(wrow);
            h8 wb = *(const h8*)(wrow + 32);
            const f32x4 t1 = *(const f32x4*)(t1sh + nt * 16 + quad * 4);
            f32x4 aA = t1, aB = t1;      // bias in accumulator (ch = 16nt+4q+r)
            aA = __builtin_amdgcn_mfma_f32_16x16x32_f16(wa, xA0, aA, 0, 0, 0);
            aA = __builtin_amdgcn_mfma_f32_16x16x32_f16(wb, xA1, aA, 0, 0, 0);
            aB = __builtin_amdgcn_mfma_f32_16x16x32_f16(wa, xB0, aB, 0, 0, 0);
            aB = __builtin_amdgcn_mfma_f32_16x16x32_f16(wb, xB1, aB, 0, 0, 0);
            u32x2 pkA = {PK(aA[0], aA[1]), PK(aA[2], aA[3])};
            u32x2 pkB = {PK(aB[0], aB[1]), PK(aB[2], aB[3])};
            *(u32x2*)(XA + l15 * XS2_ + nt * 8 + quad * 2) = pkA;
            *(u32x2*)(XB + l15 * XS2_ + nt * 8 + quad * 2) = pkB;
        }

        // ---- layer 2 NORMAL: X frags as A-operand + K-maxpool + stores ----
        h8 yA0 = *(const h8*)(XA + l15 * XS2_ + quad * 4);
        h8 yA1 = *(const h8*)(XA + l15 * XS2_ + 16 + quad * 4);
        h8 yB0 = *(const h8*)(XB + l15 * XS2_ + quad * 4);
        h8 yB1 = *(const h8*)(XB + l15 * XS2_ + 16 + quad * 4);
        float* obA = out + ((size_t)pA << 7);
        float* obB = out + ((size_t)pB << 7);
#pragma unroll 2
        for (int nt = 0; nt < 8; ++nt) {
            const _Float16* wrow = ldsW2 + (nt * 16 + l15) * WS_ + quad * 8;
            h8 wa = *(const h8*)(wrow);
            h8 wb = *(const h8*)(wrow + 32);
            const float t2 = t2sh[nt * 16 + l15];
            f32x4 aA = {0.f,0.f,0.f,0.f}, aB = {0.f,0.f,0.f,0.f};
            aA = __builtin_amdgcn_mfma_f32_16x16x32_f16(yA0, wa, aA, 0, 0, 0);
            aA = __builtin_amdgcn_mfma_f32_16x16x32_f16(yA1, wb, aA, 0, 0, 0);
            aB = __builtin_amdgcn_mfma_f32_16x16x32_f16(yB0, wa, aB, 0, 0, 0);
            aB = __builtin_amdgcn_mfma_f32_16x16x32_f16(yB1, wb, aB, 0, 0, 0);
            float vA = fmaxf(fmaxf(aA[0], aA[1]), fmaxf(aA[2], aA[3])) + t2;
            float vB = fmaxf(fmaxf(aB[0], aB[1]), fmaxf(aB[2], aB[3])) + t2;
            vA = fmaxf(vA, 0.f);  vB = fmaxf(vB, 0.f);    // relu(max)=max(relu)
            vA = fmaxf(vA, __shfl_xor(vA, 16, 64));
            vA = fmaxf(vA, __shfl_xor(vA, 32, 64));
            vB = fmaxf(vB, __shfl_xor(vB, 16, 64));
            vB = fmaxf(vB, __shfl_xor(vB, 32, 64));
            if (quad == 0) {
                obA[nt * 16 + l15]            = vA;
                obA[OUTHALF_ + nt * 16 + l15] = vA;
                obB[nt * 16 + l15]            = vB;
                obB[OUTHALF_ + nt * 16 + l15] = vB;
            }
        }

        // ---- rotate prefetched state ----
        dA = dAn; dB = dBn;
        nbA_nxt = nbA_n2; nbB_nxt = nbB_n2;
    }
}

extern "C" void kernel_launch(void* const* d_in, const int* in_sizes, int n_in,
                              void* d_out, int out_size, void* d_ws, size_t ws_size,
                              hipStream_t stream) {
    const float* xyz   = (const float*)d_in[0];
    const float* pts   = (const float*)d_in[1];
    const float* xyzs  = (const float*)d_in[2];
    const int*   nidx  = (const int*)d_in[3];
    const float* vmask = (const float*)d_in[4];
    const float *w0 = (const float*)d_in[5],  *b0 = (const float*)d_in[6],
                *g0 = (const float*)d_in[7],  *be0 = (const float*)d_in[8],
                *m0 = (const float*)d_in[9],  *v0 = (const float*)d_in[10];
    const float *w1 = (const float*)d_in[11], *b1 = (const float*)d_in[12],
                *g1 = (const float*)d_in[13], *be1 = (const float*)d_in[14],
                *m1 = (const float*)d_in[15], *v1 = (const float*)d_in[16];
    const float *w2 = (const float*)d_in[17], *b2 = (const float*)d_in[18],
                *g2 = (const float*)d_in[19], *be2 = (const float*)d_in[20],
                *m2 = (const float*)d_in[21], *v2 = (const float*)d_in[22];
    float* outp = (float*)d_out;

    const size_t PTS_ELEMS = 16777216ull;           // 4*65536*64
    if (ws_size >= PTS_ELEMS * sizeof(_Float16)) {
        _Float16* ptsh = (_Float16*)d_ws;
        cvt_pts_kernel<<<dim3(8192), dim3(256), 0, stream>>>(pts, ptsh);
        pnsa_main<true><<<dim3(GRID_), dim3(256), 0, stream>>>(
            xyz, (const void*)ptsh, xyzs, nidx, vmask,
            w0, b0, g0, be0, m0, v0,
            w1, b1, g1, be1, m1, v1,
            w2, b2, g2, be2, m2, v2, outp);
    } else {
        pnsa_main<false><<<dim3(GRID_), dim3(256), 0, stream>>>(
            xyz, (const void*)pts, xyzs, nidx, vmask,
            w0, b0, g0, be0, m0, v0,
            w1, b1, g1, be1, m1, v1,
            w2, b2, g2, be2, m2, v2, outp);
    }
}